// Round 11
// baseline (1377.053 us; speedup 1.0000x reference)
//
#include <hip/hip_runtime.h>

#define NN 100000
#define EE 1600000
#define DIN 128
#define DH 64
#define DOUT 32

#define BSH 8                      // bucket = dst >> 8  (256 nodes/bucket)
#define BNODES 256
#define NBUCK 391                  // ceil(NN/256)
#define BCAP 4608                  // fixed bucket capacity (mean 4094 + 8 sigma)
#define CHUNK 2048                 // edges per binA task
#define NCHUNK 782                 // ceil(EE/CHUNK)
#define GEMMB 782                  // ceil(NN/128) gemm tiles
#define NT12 12500                 // NN/8 gather tasks (8 nodes per 256-thread task)
#define MAXGRID 1536               // 6 blocks/CU x 256 CU

typedef unsigned short ush;
typedef __attribute__((ext_vector_type(8))) short bf16x8;
typedef __attribute__((ext_vector_type(4))) float f32x4;
typedef __attribute__((ext_vector_type(2))) float f32x2;

__device__ __forceinline__ float bflo(unsigned u) {
    union { unsigned u; float f; } c; c.u = u << 16; return c.f;
}
__device__ __forceinline__ float bfhi(unsigned u) {
    union { unsigned u; float f; } c; c.u = u & 0xffff0000u; return c.f;
}
__device__ __forceinline__ ush f2bf(float f) {
    union { float f; unsigned u; } c; c.f = f;
    unsigned r = c.u + 0x7fff + ((c.u >> 16) & 1);   // round-to-nearest-even
    return (ush)(r >> 16);
}

// -------- packed dual-f32 ops (CDNA VOP3P: add/mul/fma only — NO pk_max) --------
__device__ __forceinline__ void pka(f32x2& a, f32x2 b) {
    asm("v_pk_add_f32 %0, %0, %1" : "+v"(a) : "v"(b));
}
__device__ __forceinline__ void pkfma(f32x2& d, f32x2 a, f32x2 b) {
    asm("v_pk_fma_f32 %0, %1, %2, %0" : "+v"(d) : "v"(a), "v"(b));
}
__device__ __forceinline__ void pkmul(f32x2& a, f32x2 b) {
    asm("v_pk_mul_f32 %0, %0, %1" : "+v"(a) : "v"(b));
}
__device__ __forceinline__ f32x2 up2(unsigned u) {
    f32x2 p; p.x = bflo(u); p.y = bfhi(u); return p;
}

#define ACCW(u4, dd) { pkfma(ac0, dd, up2(u4.x)); pkfma(ac1, dd, up2(u4.y)); \
                       pkfma(ac2, dd, up2(u4.z)); pkfma(ac3, dd, up2(u4.w)); }
#define ACCP(u4) { pka(ac0, up2(u4.x)); pka(ac1, up2(u4.y)); \
                   pka(ac2, up2(u4.z)); pka(ac3, up2(u4.w)); }
#define ZINV(u4, v) { u4.x = (v) ? u4.x : 0u; u4.y = (v) ? u4.y : 0u; \
                      u4.z = (v) ? u4.z : 0u; u4.w = (v) ? u4.w : 0u; }
#define BFLY(msk) { f32x2 t_;                                           \
    t_.x = __shfl_xor(ac0.x, msk); t_.y = __shfl_xor(ac0.y, msk); pka(ac0, t_); \
    t_.x = __shfl_xor(ac1.x, msk); t_.y = __shfl_xor(ac1.y, msk); pka(ac1, t_); \
    t_.x = __shfl_xor(ac2.x, msk); t_.y = __shfl_xor(ac2.y, msk); pka(ac2, t_); \
    t_.x = __shfl_xor(ac3.x, msk); t_.y = __shfl_xor(ac3.y, msk); pka(ac3, t_); }

// ---------------- init: zero barrier words, set bucket cursors ----------------
__global__ void init_kernel(int* __restrict__ bar, int* __restrict__ bcur) {
    int i = blockIdx.x * 256 + threadIdx.x;
    if (i < 8) bar[i] = 0;
    if (i < NBUCK) bcur[i] = i * BCAP;
}

// ---------------- device-wide barrier, SYSTEM scope (cross-XCD safe) ----------------
__device__ __forceinline__ void gbar(int* bar) {
    __syncthreads();
    if (threadIdx.x == 0) {
        __threadfence_system();
        int g = __hip_atomic_load(&bar[1], __ATOMIC_RELAXED, __HIP_MEMORY_SCOPE_SYSTEM);
        int old = __hip_atomic_fetch_add(&bar[0], 1, __ATOMIC_SEQ_CST, __HIP_MEMORY_SCOPE_SYSTEM);
        if (old == (int)gridDim.x - 1) {
            __hip_atomic_store(&bar[0], 0, __ATOMIC_RELAXED, __HIP_MEMORY_SCOPE_SYSTEM);
            __hip_atomic_store(&bar[1], g + 1, __ATOMIC_SEQ_CST, __HIP_MEMORY_SCOPE_SYSTEM);
        } else {
            while (__hip_atomic_load(&bar[1], __ATOMIC_ACQUIRE, __HIP_MEMORY_SCOPE_SYSTEM) == g)
                __builtin_amdgcn_s_sleep(8);
        }
        __threadfence_system();
    }
    __syncthreads();
}

union __align__(16) MegaLDS {
    struct {                                                // binA (22.7 KB, R7-proven)
        int hist[NBUCK], scn[NBUCK], cur[NBUCK], gb[NBUCK];
        int wtot[4];
        unsigned staged[CHUNK];
        int gaddr[CHUNK];
    } a;
    struct { int hist[BNODES], cur[BNODES], wtot[4]; } b;   // binB (2.1 KB)
    ush wt[DH * (DIN + 8)];                                 // gemm (17.4 KB)
    float wp[32 * 68];                                      // g1 W2 (8.7 KB)
};

// ---------------- mega kernel: A:binA | B:binB+gemm1 | C:g1+gemm2 | D:g2+fc ---------
__global__ __launch_bounds__(256, 6) void mega_kernel(
        const int* __restrict__ src, const int* __restrict__ dst,
        const float* __restrict__ x, const float* __restrict__ W1,
        const float* __restrict__ b1, const float* __restrict__ W2,
        const float* __restrict__ b2, const float* __restrict__ fcw,
        const float* __restrict__ fcb,
        int* __restrict__ bar, int* __restrict__ bcur,
        unsigned* __restrict__ tmp, int* __restrict__ csr,
        int* __restrict__ offs, int* __restrict__ ends, float* __restrict__ dinv,
        ush* __restrict__ Hs1, ush* __restrict__ Hs2,
        float* __restrict__ h2g, float* __restrict__ scores) {
    __shared__ MegaLDS L;
    const int t = threadIdx.x;

    // ================= PHASE A: edge binning (R7-proven body, verbatim) ===========
    for (int task = blockIdx.x; task < NCHUNK; task += gridDim.x) {
        const int lane = t & 63, w = t >> 6;
        for (int i = t; i < NBUCK; i += 256) L.a.hist[i] = 0;
        __syncthreads();
        int e0 = task * CHUNK;
        int nE = min(CHUNK, EE - e0);
        int my_e[CHUNK / 256], my_bk[CHUNK / 256];
#pragma unroll
        for (int k = 0; k < CHUNK / 256; k++) {
            int li = t + k * 256;
            bool ok = li < nE;
            int idx = ok ? (e0 + li) : e0;
            int d = dst[idx];
            int sv = src[idx];
            int b = d >> BSH;
            my_e[k] = (sv << 8) | (d & 255);
            my_bk[k] = ok ? b : -1;
            if (ok) atomicAdd(&L.a.hist[b], 1);
        }
        __syncthreads();
        int a0 = (2 * t < NBUCK) ? L.a.hist[2 * t] : 0;
        int a1 = (2 * t + 1 < NBUCK) ? L.a.hist[2 * t + 1] : 0;
        int s = a0 + a1;
#pragma unroll
        for (int off = 1; off < 64; off <<= 1) {
            int v = __shfl_up(s, off);
            if (lane >= off) s += v;
        }
        if (lane == 63) L.a.wtot[w] = s;
        __syncthreads();
        int pre = 0;
#pragma unroll
        for (int i = 0; i < 4; i++) pre += (i < w) ? L.a.wtot[i] : 0;
        int excl = s + pre - a0 - a1;
        if (2 * t < NBUCK)     { L.a.scn[2 * t] = excl;          L.a.cur[2 * t] = excl; }
        if (2 * t + 1 < NBUCK) { L.a.scn[2 * t + 1] = excl + a0; L.a.cur[2 * t + 1] = excl + a0; }
        __syncthreads();
        for (int i = t; i < NBUCK; i += 256) {
            int h = L.a.hist[i];
            if (h) L.a.gb[i] = atomicAdd(&bcur[i], h) - L.a.scn[i];
        }
        __syncthreads();
#pragma unroll
        for (int k = 0; k < CHUNK / 256; k++) {
            int b = my_bk[k];
            if (b >= 0) {
                int lp = atomicAdd(&L.a.cur[b], 1);
                L.a.staged[lp] = (unsigned)my_e[k];
                L.a.gaddr[lp] = L.a.gb[b] + lp;
            }
        }
        __syncthreads();
        for (int i = t; i < nE; i += 256)
            tmp[L.a.gaddr[i]] = L.a.staged[i];
        __syncthreads();
    }
    gbar(bar);

    // ================= PHASE B: binB (391) + gemm1 RAW (782) ======================
    for (int task = blockIdx.x; task < NBUCK + GEMMB; task += gridDim.x) {
        if (task < NBUCK) {
            int b = task;
            int e0 = b * BCAP, e1 = bcur[b];
            const int lane = t & 63, w = t >> 6;
            L.b.hist[t] = 0;
            __syncthreads();
            for (int i = e0 + t; i < e1; i += 256) atomicAdd(&L.b.hist[tmp[i] & 255], 1);
            __syncthreads();
            int v = L.b.hist[t];
            int s = v;
#pragma unroll
            for (int off = 1; off < 64; off <<= 1) {
                int xv = __shfl_up(s, off);
                if (lane >= off) s += xv;
            }
            if (lane == 63) L.b.wtot[w] = s;
            __syncthreads();
            int pre = 0;
#pragma unroll
            for (int i = 0; i < 4; i++) pre += (i < w) ? L.b.wtot[i] : 0;
            int excl = s + pre - v;
            L.b.cur[t] = e0 + excl;
            int node = (b << BSH) + t;
            if (node < NN) {
                offs[node] = e0 + excl;
                ends[node] = e0 + excl + v;
                dinv[node] = 1.0f / sqrtf((float)v + 1.0f);
            }
            __syncthreads();
            for (int i = e0 + t; i < e1; i += 256) {
                unsigned u = tmp[i];
                int pos = atomicAdd(&L.b.cur[u & 255], 1);
                csr[pos] = (int)(u >> 8);
            }
            __syncthreads();
        } else {
            // ---- gemm1 RAW: Hs1 = bf16(x@W1), 128-row tile ----
            constexpr int KP = DIN + 8;
            constexpr int NCT = DH / 16;
            const int row0 = (task - NBUCK) * 128;
            for (int i = t; i < DIN * (DH / 4); i += 256) {
                int k = i / (DH / 4), n4 = i % (DH / 4);
                float4 v = *(const float4*)&W1[k * DH + n4 * 4];
                L.wt[(n4 * 4 + 0) * KP + k] = f2bf(v.x);
                L.wt[(n4 * 4 + 1) * KP + k] = f2bf(v.y);
                L.wt[(n4 * 4 + 2) * KP + k] = f2bf(v.z);
                L.wt[(n4 * 4 + 3) * KP + k] = f2bf(v.w);
            }
            __syncthreads();
            const int wave = t >> 6, lane = t & 63;
            const int m = lane & 15, quad = lane >> 4;
            const int wrow = wave * 32;
            f32x4 acc[2][NCT];
#pragma unroll
            for (int rt = 0; rt < 2; rt++)
#pragma unroll
                for (int ct = 0; ct < NCT; ct++) acc[rt][ct] = (f32x4){0.f, 0.f, 0.f, 0.f};
#pragma unroll
            for (int kc = 0; kc < DIN / 32; kc++) {
                int koff = kc * 32 + quad * 8;
                bf16x8 bfr[NCT];
#pragma unroll
                for (int ct = 0; ct < NCT; ct++)
                    bfr[ct] = *(const bf16x8*)&L.wt[(ct * 16 + m) * KP + koff];
#pragma unroll
                for (int rt = 0; rt < 2; rt++) {
                    int row = row0 + wrow + rt * 16 + m;
                    float4 va = make_float4(0.f, 0.f, 0.f, 0.f), vb = va;
                    if (row < NN) {
                        va = *(const float4*)&x[(size_t)row * DIN + koff];
                        vb = *(const float4*)&x[(size_t)row * DIN + koff + 4];
                    }
                    union { bf16x8 v; ush s[8]; } A;
                    A.s[0] = f2bf(va.x); A.s[1] = f2bf(va.y); A.s[2] = f2bf(va.z); A.s[3] = f2bf(va.w);
                    A.s[4] = f2bf(vb.x); A.s[5] = f2bf(vb.y); A.s[6] = f2bf(vb.z); A.s[7] = f2bf(vb.w);
#pragma unroll
                    for (int ct = 0; ct < NCT; ct++)
                        acc[rt][ct] = __builtin_amdgcn_mfma_f32_16x16x32_bf16(A.v, bfr[ct], acc[rt][ct], 0, 0, 0);
                }
            }
#pragma unroll
            for (int rt = 0; rt < 2; rt++) {
#pragma unroll
                for (int reg = 0; reg < 4; reg++) {
                    int row = row0 + wrow + rt * 16 + quad * 4 + reg;
                    if (row < NN) {
#pragma unroll
                        for (int ct = 0; ct < NCT; ct++)
                            Hs1[(size_t)row * DH + ct * 16 + m] = f2bf(acc[rt][ct][reg]);
                    }
                }
            }
            __syncthreads();
        }
    }
    gbar(bar);

    // ================= PHASE C: gather1 + gemm2 fused ============================
    {   // stage W2 per-lane 8x8 f32 partitions once (stride 68 floats = 272 B)
        int lp = t >> 3, r = t & 7;
        int srow = (lp & 7) * 8 + r, scol = (lp >> 3) * 8;
        float4 va = *(const float4*)&W2[srow * DOUT + scol];
        float4 vb = *(const float4*)&W2[srow * DOUT + scol + 4];
        *(float4*)&L.wp[lp * 68 + r * 8] = va;
        *(float4*)&L.wp[lp * 68 + r * 8 + 4] = vb;
    }
    __syncthreads();
    for (int task = blockIdx.x; task < NT12; task += gridDim.x) {
        const int lane = t & 63;
        int node = task * 8 + (t >> 6) * 2 + (lane >> 5);    // NT12*8 == NN exactly
        int l = lane & 31;
        int es = l >> 3;
        int fg = l & 7;
        int start = offs[node], end = ends[node];
        float dv = dinv[node];
        uint4 su = *(const uint4*)&Hs1[node * DH + fg * 8];
        f32x2 ac0 = {0.f, 0.f}, ac1 = {0.f, 0.f}, ac2 = {0.f, 0.f}, ac3 = {0.f, 0.f};
        int base = start + es;
        {   // 6 predicated batches (deg<=24, ~98%), all loads in flight
            int p0 = base, p1 = base + 4, p2 = base + 8,
                p3 = base + 12, p4 = base + 16, p5 = base + 20;
            bool v0 = p0 < end, v1 = p1 < end, v2 = p2 < end,
                 v3 = p3 < end, v4 = p4 < end, v5 = p5 < end;
            int s0 = csr[v0 ? p0 : 0], s1 = csr[v1 ? p1 : 0], s2 = csr[v2 ? p2 : 0],
                s3 = csr[v3 ? p3 : 0], s4 = csr[v4 ? p4 : 0], s5 = csr[v5 ? p5 : 0];
            float d0 = v0 ? dinv[s0] : 0.f, d1 = v1 ? dinv[s1] : 0.f,
                  d2 = v2 ? dinv[s2] : 0.f, d3 = v3 ? dinv[s3] : 0.f,
                  d4 = v4 ? dinv[s4] : 0.f, d5 = v5 ? dinv[s5] : 0.f;
            uint4 u0 = *(const uint4*)&Hs1[s0 * DH + fg * 8];
            uint4 u1 = *(const uint4*)&Hs1[s1 * DH + fg * 8];
            uint4 u2 = *(const uint4*)&Hs1[s2 * DH + fg * 8];
            uint4 u3 = *(const uint4*)&Hs1[s3 * DH + fg * 8];
            uint4 u4 = *(const uint4*)&Hs1[s4 * DH + fg * 8];
            uint4 u5 = *(const uint4*)&Hs1[s5 * DH + fg * 8];
            f32x2 dd;
            dd.x = d0; dd.y = d0; ACCW(u0, dd)
            dd.x = d1; dd.y = d1; ACCW(u1, dd)
            dd.x = d2; dd.y = d2; ACCW(u2, dd)
            dd.x = d3; dd.y = d3; ACCW(u3, dd)
            dd.x = d4; dd.y = d4; ACCW(u4, dd)
            dd.x = d5; dd.y = d5; ACCW(u5, dd)
        }
        for (int k = base + 24; k < end; k += 4) {
            int s = csr[k];
            float d = dinv[s];
            uint4 u = *(const uint4*)&Hs1[s * DH + fg * 8];
            f32x2 dd; dd.x = d; dd.y = d;
            ACCW(u, dd)
        }
        BFLY(8) BFLY(16)
        float4 ba = *(const float4*)&b1[fg * 8];
        float4 bb = *(const float4*)&b1[fg * 8 + 4];
        f32x2 dvp; dvp.x = dv; dvp.y = dv;
        pkfma(ac0, dvp, up2(su.x)); pkfma(ac1, dvp, up2(su.y));
        pkfma(ac2, dvp, up2(su.z)); pkfma(ac3, dvp, up2(su.w));
        f32x2 h0; h0.x = ba.x; h0.y = ba.y;
        f32x2 h1; h1.x = ba.z; h1.y = ba.w;
        f32x2 h2; h2.x = bb.x; h2.y = bb.y;
        f32x2 h3; h3.x = bb.z; h3.y = bb.w;
        pkfma(h0, dvp, ac0); pkfma(h1, dvp, ac1); pkfma(h2, dvp, ac2); pkfma(h3, dvp, ac3);
        h0.x = fmaxf(h0.x, 0.f); h0.y = fmaxf(h0.y, 0.f);
        h1.x = fmaxf(h1.x, 0.f); h1.y = fmaxf(h1.y, 0.f);
        h2.x = fmaxf(h2.x, 0.f); h2.y = fmaxf(h2.y, 0.f);
        h3.x = fmaxf(h3.x, 0.f); h3.y = fmaxf(h3.y, 0.f);
        const float* wl = &L.wp[l * 68];
        float hs_[8] = {h0.x, h0.y, h1.x, h1.y, h2.x, h2.y, h3.x, h3.y};
        f32x2 p0 = {0.f, 0.f}, p1 = {0.f, 0.f}, p2 = {0.f, 0.f}, p3 = {0.f, 0.f};
#pragma unroll
        for (int r = 0; r < 8; r++) {
            float4 wa = *(const float4*)&wl[r * 8];
            float4 wb = *(const float4*)&wl[r * 8 + 4];
            f32x2 hr; hr.x = hs_[r]; hr.y = hs_[r];
            f32x2 w01; w01.x = wa.x; w01.y = wa.y;
            f32x2 w23; w23.x = wa.z; w23.y = wa.w;
            f32x2 w45; w45.x = wb.x; w45.y = wb.y;
            f32x2 w67; w67.x = wb.z; w67.y = wb.w;
            pkfma(p0, hr, w01); pkfma(p1, hr, w23);
            pkfma(p2, hr, w45); pkfma(p3, hr, w67);
        }
#pragma unroll
        for (int msk = 1; msk <= 4; msk <<= 1) {
            f32x2 t_;
            t_.x = __shfl_xor(p0.x, msk); t_.y = __shfl_xor(p0.y, msk); pka(p0, t_);
            t_.x = __shfl_xor(p1.x, msk); t_.y = __shfl_xor(p1.y, msk); pka(p1, t_);
            t_.x = __shfl_xor(p2.x, msk); t_.y = __shfl_xor(p2.y, msk); pka(p2, t_);
            t_.x = __shfl_xor(p3.x, msk); t_.y = __shfl_xor(p3.y, msk); pka(p3, t_);
        }
        if (fg == 0) {
            pkmul(p0, dvp); pkmul(p1, dvp); pkmul(p2, dvp); pkmul(p3, dvp);
            ushort4 oa, ob;
            oa.x = f2bf(p0.x); oa.y = f2bf(p0.y); oa.z = f2bf(p1.x); oa.w = f2bf(p1.y);
            ob.x = f2bf(p2.x); ob.y = f2bf(p2.y); ob.z = f2bf(p3.x); ob.w = f2bf(p3.y);
            *(ushort4*)&Hs2[node * DOUT + es * 8] = oa;
            *(ushort4*)&Hs2[node * DOUT + es * 8 + 4] = ob;
        }
    }
    gbar(bar);

    // ================= PHASE D: gather2 + fc =====================================
    for (int task = blockIdx.x; task < NT12; task += gridDim.x) {
        const int lane = t & 63;
        int node = task * 8 + (t >> 6) * 2 + (lane >> 5);
        int l = lane & 31;
        int es = l >> 2;
        int fg = l & 3;
        int start = offs[node], end = ends[node];
        float dv = dinv[node];
        uint4 su = *(const uint4*)&Hs2[node * DOUT + fg * 8];
        f32x2 ac0 = {0.f, 0.f}, ac1 = {0.f, 0.f}, ac2 = {0.f, 0.f}, ac3 = {0.f, 0.f};
        int base = start + es;
        {   // 4 predicated batches (deg<=32)
            int p0 = base, p1 = base + 8, p2 = base + 16, p3 = base + 24;
            bool v0 = p0 < end, v1 = p1 < end, v2 = p2 < end, v3 = p3 < end;
            int s0 = csr[v0 ? p0 : 0], s1 = csr[v1 ? p1 : 0],
                s2 = csr[v2 ? p2 : 0], s3 = csr[v3 ? p3 : 0];
            uint4 u0 = *(const uint4*)&Hs2[s0 * DOUT + fg * 8];
            uint4 u1 = *(const uint4*)&Hs2[s1 * DOUT + fg * 8];
            uint4 u2 = *(const uint4*)&Hs2[s2 * DOUT + fg * 8];
            uint4 u3 = *(const uint4*)&Hs2[s3 * DOUT + fg * 8];
            ZINV(u0, v0) ZINV(u1, v1) ZINV(u2, v2) ZINV(u3, v3)
            ACCP(u0) ACCP(u1) ACCP(u2) ACCP(u3)
        }
        for (int k = base + 32; k < end; k += 8) {
            int s = csr[k];
            uint4 u = *(const uint4*)&Hs2[s * DOUT + fg * 8];
            ACCP(u)
        }
        BFLY(4) BFLY(8) BFLY(16)
        float4 ba = *(const float4*)&b2[fg * 8];
        float4 bb = *(const float4*)&b2[fg * 8 + 4];
        f32x2 dvp; dvp.x = dv; dvp.y = dv;
        pka(ac0, up2(su.x)); pka(ac1, up2(su.y)); pka(ac2, up2(su.z)); pka(ac3, up2(su.w));
        f32x2 h0; h0.x = ba.x; h0.y = ba.y;
        f32x2 h1; h1.x = ba.z; h1.y = ba.w;
        f32x2 h2v; h2v.x = bb.x; h2v.y = bb.y;
        f32x2 h3; h3.x = bb.z; h3.y = bb.w;
        pkfma(h0, dvp, ac0); pkfma(h1, dvp, ac1); pkfma(h2v, dvp, ac2); pkfma(h3, dvp, ac3);
        h0.x = fmaxf(h0.x, 0.f); h0.y = fmaxf(h0.y, 0.f);
        h1.x = fmaxf(h1.x, 0.f); h1.y = fmaxf(h1.y, 0.f);
        h2v.x = fmaxf(h2v.x, 0.f); h2v.y = fmaxf(h2v.y, 0.f);
        h3.x = fmaxf(h3.x, 0.f); h3.y = fmaxf(h3.y, 0.f);
        if (es == 0) {
            float4 o0, o1;
            o0.x = h0.x; o0.y = h0.y; o0.z = h1.x; o0.w = h1.y;
            o1.x = h2v.x; o1.y = h2v.y; o1.z = h3.x; o1.w = h3.y;
            *(float4*)&h2g[node * DOUT + fg * 8] = o0;
            *(float4*)&h2g[node * DOUT + fg * 8 + 4] = o1;
        }
        float4 fa = *(const float4*)&fcw[fg * 8];
        float4 fb = *(const float4*)&fcw[fg * 8 + 4];
        f32x2 dp = {0.f, 0.f};
        f32x2 f01; f01.x = fa.x; f01.y = fa.y;
        f32x2 f23; f23.x = fa.z; f23.y = fa.w;
        f32x2 f45; f45.x = fb.x; f45.y = fb.y;
        f32x2 f67; f67.x = fb.z; f67.y = fb.w;
        pkfma(dp, h0, f01); pkfma(dp, h1, f23); pkfma(dp, h2v, f45); pkfma(dp, h3, f67);
        float sv = dp.x + dp.y;
        sv += __shfl_xor(sv, 1); sv += __shfl_xor(sv, 2);
        if (l == 0) scores[node] = sv + fcb[0];
    }
}

extern "C" void kernel_launch(void* const* d_in, const int* in_sizes, int n_in,
                              void* d_out, int out_size, void* d_ws, size_t ws_size,
                              hipStream_t stream) {
    const float* x   = (const float*)d_in[0];
    const int*   ei  = (const int*)d_in[1];
    const float* W1  = (const float*)d_in[2];
    const float* b1  = (const float*)d_in[3];
    const float* W2  = (const float*)d_in[4];
    const float* b2  = (const float*)d_in[5];
    const float* fcw = (const float*)d_in[6];
    const float* fcb = (const float*)d_in[7];
    const int* src = ei;
    const int* dst = ei + EE;

    // Workspace layout (float-index units). CAREFUL: Hs1 is NN*64 bf16 = 12.8 MB
    // = 3,200,000 floats -> occupies [3905024, 7105024). R9/R10 placed Hs2 at
    // 5505024 INSIDE that range -> deterministic corruption (absmax 468). Fixed.
    float* ws = (float*)d_ws;
    int*   bar     = (int*)ws;                    // [0,8) ints
    int*   bcur    = (int*)(ws + 16);             // [16,407) ints
    float* dinv    = ws + 512;                    // [512, 100512)
    int*   offs    = (int*)(ws + 100864);         // [100864, 200864)
    int*   ends    = (int*)(ws + 201216);         // [201216, 301216)
    unsigned* tmp  = (unsigned*)(ws + 301568);    // [301568, 2103296)  NBUCK*BCAP
    int*   csr     = (int*)(ws + 2103296);        // [2103296, 3905024) NBUCK*BCAP
    ush*   Hs1     = (ush*)(ws + 3905024);        // [3905024, 7105024) NN*64 bf16
    ush*   Hs2     = (ush*)(ws + 7105024);        // [7105024, 8705024) NN*32 bf16

    float* out    = (float*)d_out;
    float* scores = out;          // NN
    float* h2g    = out + NN;     // NN*32

    // grid sized from actual CU count so all blocks are guaranteed co-resident:
    // 6 blocks/CU enforced by __launch_bounds__(256,6) + 22.7KB LDS (7/CU limit).
    static int grid = 0;
    if (!grid) {
        hipDeviceProp_t p;
        hipGetDeviceProperties(&p, 0);
        int g = p.multiProcessorCount * 6;
        grid = (g > MAXGRID) ? MAXGRID : g;
        if (grid < 64) grid = 64;
    }

    init_kernel<<<2, 256, 0, stream>>>(bar, bcur);
    mega_kernel<<<grid, 256, 0, stream>>>(src, dst, x, W1, b1, W2, b2, fcw, fcb,
                                          bar, bcur, tmp, csr, offs, ends, dinv,
                                          Hs1, Hs2, h2g, scores);
}

// Round 12
// 223.591 us; speedup vs baseline: 6.1588x; 6.1588x over previous
//
#include <hip/hip_runtime.h>

#define NN 100000
#define EE 1600000
#define DIN 128
#define DH 64
#define DOUT 32

#define BSH 8                      // bucket = dst >> 8  (256 nodes/bucket)
#define BNODES 256
#define NBUCK ((NN + BNODES - 1) / BNODES)   // 391
#define BCAP 4608                  // fixed bucket capacity (mean 4094 + 8 sigma)
#define CHUNK 2048                 // edges per binA block
#define NCHUNK ((EE + CHUNK - 1) / CHUNK)    // 782
#define GEMMB ((NN + 127) / 128)             // 782 gemm blocks in the fat dispatch

typedef unsigned short ush;
typedef __attribute__((ext_vector_type(8))) short bf16x8;
typedef __attribute__((ext_vector_type(4))) float f32x4;
typedef __attribute__((ext_vector_type(2))) float f32x2;

__device__ __forceinline__ float bflo(unsigned u) {
    union { unsigned u; float f; } c; c.u = u << 16; return c.f;
}
__device__ __forceinline__ float bfhi(unsigned u) {
    union { unsigned u; float f; } c; c.u = u & 0xffff0000u; return c.f;
}
__device__ __forceinline__ ush f2bf(float f) {
    union { float f; unsigned u; } c; c.f = f;
    unsigned r = c.u + 0x7fff + ((c.u >> 16) & 1);   // round-to-nearest-even
    return (ush)(r >> 16);
}

// -------- packed dual-f32 ops (CDNA VOP3P: add/mul/fma only — NO pk_max) --------
__device__ __forceinline__ void pka(f32x2& a, f32x2 b) {          // a += b
    asm("v_pk_add_f32 %0, %0, %1" : "+v"(a) : "v"(b));
}
__device__ __forceinline__ void pkfma(f32x2& d, f32x2 a, f32x2 b) { // d += a*b
    asm("v_pk_fma_f32 %0, %1, %2, %0" : "+v"(d) : "v"(a), "v"(b));
}
__device__ __forceinline__ void pkmul(f32x2& a, f32x2 b) {        // a *= b
    asm("v_pk_mul_f32 %0, %0, %1" : "+v"(a) : "v"(b));
}
__device__ __forceinline__ f32x2 up2(unsigned u) {                // (bf16 lo, bf16 hi) -> 2 f32
    f32x2 p; p.x = bflo(u); p.y = bfhi(u); return p;
}

// ---------------- init bucket cursors to fixed bases ----------------
__global__ void init_bcur_kernel(int* __restrict__ bcur) {
    int i = blockIdx.x * 256 + threadIdx.x;
    if (i < NBUCK) bcur[i] = i * BCAP;
}

// ---------------- fat dispatch: blocks [0,NCHUNK) = binA; [NCHUNK,+GEMMB) = gemm1 -----
// binA: bin 2048 edges into fixed-capacity buckets (packed (src<<8)|dstlow).
// gemm1: Hs1 = bf16(x@W1) RAW (no dinv dep — binB scales Hs1 in place afterwards).
// Proven at 53.6 us in R6 (binA's latency bubbles absorb the gemm blocks).
union __align__(16) FatLDS {
    struct {
        int hist[NBUCK], scn[NBUCK], cur[NBUCK], gb[NBUCK];
        int wtot[4];
        unsigned staged[CHUNK];
        int gaddr[CHUNK];
    } a;
    struct {
        ush wt[DH * (DIN + 8)];
    } g;
};

__global__ __launch_bounds__(256) void fatAG_kernel(const int* __restrict__ src,
                                                    const int* __restrict__ dst,
                                                    int* __restrict__ bcur,
                                                    unsigned* __restrict__ tmp,
                                                    const float* __restrict__ x,
                                                    const float* __restrict__ W1,
                                                    ush* __restrict__ Hs1) {
    __shared__ FatLDS L;
    const int t = threadIdx.x;

    if (blockIdx.x < NCHUNK) {
        // ---------------- binA ----------------
        const int lane = t & 63, w = t >> 6;
        for (int i = t; i < NBUCK; i += 256) L.a.hist[i] = 0;
        __syncthreads();
        int e0 = blockIdx.x * CHUNK;
        int nE = min(CHUNK, EE - e0);

        int my_e[CHUNK / 256], my_bk[CHUNK / 256];
#pragma unroll
        for (int k = 0; k < CHUNK / 256; k++) {
            int li = t + k * 256;
            bool ok = li < nE;
            int idx = ok ? (e0 + li) : e0;
            int d = dst[idx];
            int s = src[idx];
            int b = d >> BSH;
            my_e[k] = (s << 8) | (d & 255);
            my_bk[k] = ok ? b : -1;
            if (ok) atomicAdd(&L.a.hist[b], 1);
        }
        __syncthreads();
        // wave-shuffle scan over 2 entries/thread (covers NBUCK=391 < 512)
        int a0 = (2 * t < NBUCK) ? L.a.hist[2 * t] : 0;
        int a1 = (2 * t + 1 < NBUCK) ? L.a.hist[2 * t + 1] : 0;
        int s = a0 + a1;
#pragma unroll
        for (int off = 1; off < 64; off <<= 1) {
            int v = __shfl_up(s, off);
            if (lane >= off) s += v;
        }
        if (lane == 63) L.a.wtot[w] = s;
        __syncthreads();
        int pre = 0;
#pragma unroll
        for (int i = 0; i < 4; i++) pre += (i < w) ? L.a.wtot[i] : 0;
        int excl = s + pre - a0 - a1;
        if (2 * t < NBUCK)     { L.a.scn[2 * t] = excl;          L.a.cur[2 * t] = excl; }
        if (2 * t + 1 < NBUCK) { L.a.scn[2 * t + 1] = excl + a0; L.a.cur[2 * t + 1] = excl + a0; }
        __syncthreads();
        for (int i = t; i < NBUCK; i += 256) {
            int h = L.a.hist[i];
            if (h) L.a.gb[i] = atomicAdd(&bcur[i], h) - L.a.scn[i];
        }
        __syncthreads();
#pragma unroll
        for (int k = 0; k < CHUNK / 256; k++) {
            int b = my_bk[k];
            if (b >= 0) {
                int lp = atomicAdd(&L.a.cur[b], 1);
                L.a.staged[lp] = (unsigned)my_e[k];
                L.a.gaddr[lp] = L.a.gb[b] + lp;
            }
        }
        __syncthreads();
        for (int i = t; i < nE; i += 256)
            tmp[L.a.gaddr[i]] = L.a.staged[i];
        return;
    }

    // ---------------- gemm1 RAW (K=DIN=128, NC=DH=64): Hs1 = bf16(x@W1) -------------
    constexpr int KP = DIN + 8;          // 136
    constexpr int NCT = DH / 16;         // 4 col tiles
    const int row0 = (blockIdx.x - NCHUNK) * 128;
    for (int i = t; i < DIN * (DH / 4); i += 256) {
        int k = i / (DH / 4), n4 = i % (DH / 4);
        float4 v = *(const float4*)&W1[k * DH + n4 * 4];
        L.g.wt[(n4 * 4 + 0) * KP + k] = f2bf(v.x);
        L.g.wt[(n4 * 4 + 1) * KP + k] = f2bf(v.y);
        L.g.wt[(n4 * 4 + 2) * KP + k] = f2bf(v.z);
        L.g.wt[(n4 * 4 + 3) * KP + k] = f2bf(v.w);
    }
    __syncthreads();

    const int wave = t >> 6, lane = t & 63;
    const int m = lane & 15, quad = lane >> 4;
    const int wrow = wave * 32;

    f32x4 acc[2][NCT];
#pragma unroll
    for (int rt = 0; rt < 2; rt++)
#pragma unroll
        for (int ct = 0; ct < NCT; ct++) acc[rt][ct] = (f32x4){0.f, 0.f, 0.f, 0.f};

#pragma unroll
    for (int kc = 0; kc < DIN / 32; kc++) {
        int koff = kc * 32 + quad * 8;
        bf16x8 bfr[NCT];
#pragma unroll
        for (int ct = 0; ct < NCT; ct++)
            bfr[ct] = *(const bf16x8*)&L.g.wt[(ct * 16 + m) * KP + koff];
#pragma unroll
        for (int rt = 0; rt < 2; rt++) {
            int row = row0 + wrow + rt * 16 + m;
            float4 va = make_float4(0.f, 0.f, 0.f, 0.f), vb = va;
            if (row < NN) {
                va = *(const float4*)&x[(size_t)row * DIN + koff];
                vb = *(const float4*)&x[(size_t)row * DIN + koff + 4];
            }
            union { bf16x8 v; ush s[8]; } A;
            A.s[0] = f2bf(va.x); A.s[1] = f2bf(va.y); A.s[2] = f2bf(va.z); A.s[3] = f2bf(va.w);
            A.s[4] = f2bf(vb.x); A.s[5] = f2bf(vb.y); A.s[6] = f2bf(vb.z); A.s[7] = f2bf(vb.w);
#pragma unroll
            for (int ct = 0; ct < NCT; ct++)
                acc[rt][ct] = __builtin_amdgcn_mfma_f32_16x16x32_bf16(A.v, bfr[ct], acc[rt][ct], 0, 0, 0);
        }
    }
#pragma unroll
    for (int rt = 0; rt < 2; rt++) {
#pragma unroll
        for (int reg = 0; reg < 4; reg++) {
            int row = row0 + wrow + rt * 16 + quad * 4 + reg;
            if (row < NN) {
#pragma unroll
                for (int ct = 0; ct < NCT; ct++)
                    Hs1[(size_t)row * DH + ct * 16 + m] = f2bf(acc[rt][ct][reg]);
            }
        }
    }
}

// ---------------- Pass B + scale: histogram/scan -> offs/ends/dinv/csr, then
// scale this bucket's 256 Hs1 rows in place by dinv (raw -> pre-scaled).
// This removes gemm1's dinv dependency (enabling fatAG) while keeping gather1
// in its cheap pre-scaled form (no per-edge dinv loads).
__global__ __launch_bounds__(256) void binBs_kernel(const unsigned* __restrict__ tmp,
                                                    const int* __restrict__ bcur,
                                                    int* __restrict__ csr,
                                                    int* __restrict__ offs,
                                                    int* __restrict__ ends,
                                                    float* __restrict__ dinv,
                                                    ush* __restrict__ Hs1) {
    __shared__ int hist[BNODES], cur[BNODES];
    __shared__ int wtot[4];
    int b = blockIdx.x, t = threadIdx.x;
    const int lane = t & 63, w = t >> 6;
    int e0 = b * BCAP, e1 = bcur[b];
    hist[t] = 0;
    __syncthreads();
    for (int i = e0 + t; i < e1; i += 256) atomicAdd(&hist[tmp[i] & 255], 1);
    __syncthreads();
    int v = hist[t];
    int s = v;
#pragma unroll
    for (int off = 1; off < 64; off <<= 1) {
        int x = __shfl_up(s, off);
        if (lane >= off) s += x;
    }
    if (lane == 63) wtot[w] = s;
    __syncthreads();
    int pre = 0;
#pragma unroll
    for (int i = 0; i < 4; i++) pre += (i < w) ? wtot[i] : 0;
    int excl = s + pre - v;
    cur[t] = e0 + excl;
    int node = (b << BSH) + t;
    float dvl = 1.0f / sqrtf((float)v + 1.0f);
    if (node < NN) {
        offs[node] = e0 + excl;
        ends[node] = e0 + excl + v;
        dinv[node] = dvl;
    }
    __syncthreads();
    for (int i = e0 + t; i < e1; i += 256) {
        unsigned u = tmp[i];
        int pos = atomicAdd(&cur[u & 255], 1);
        csr[pos] = (int)(u >> 8);
    }
    // scale Hs1 row of this node: raw bf16(x@W1) -> bf16(raw * dinv)
    if (node < NN) {
        ush* row = &Hs1[(size_t)node * DH];
#pragma unroll
        for (int c = 0; c < 8; c++) {
            uint4 u4 = *(const uint4*)&row[c * 8];
            ushort4 oa, ob;
            oa.x = f2bf(bflo(u4.x) * dvl); oa.y = f2bf(bfhi(u4.x) * dvl);
            oa.z = f2bf(bflo(u4.y) * dvl); oa.w = f2bf(bfhi(u4.y) * dvl);
            ob.x = f2bf(bflo(u4.z) * dvl); ob.y = f2bf(bfhi(u4.z) * dvl);
            ob.z = f2bf(bflo(u4.w) * dvl); ob.w = f2bf(bfhi(u4.w) * dvl);
            *(ushort4*)&row[c * 8] = oa;
            *(ushort4*)&row[c * 8 + 4] = ob;
        }
    }
}

// packed accumulate of a 4-uint (8 bf16) row chunk into 4 f32x2 accumulators
#define ACCP(u4) { pka(ac0, up2(u4.x)); pka(ac1, up2(u4.y)); \
                   pka(ac2, up2(u4.z)); pka(ac3, up2(u4.w)); }

// zero an invalid batch's row before accumulation (v_cndmask x4)
#define ZINV(u4, v) { u4.x = (v) ? u4.x : 0u; u4.y = (v) ? u4.y : 0u; \
                      u4.z = (v) ? u4.z : 0u; u4.w = (v) ? u4.w : 0u; }

#define BFLY(msk) { f32x2 t_;                                           \
    t_.x = __shfl_xor(ac0.x, msk); t_.y = __shfl_xor(ac0.y, msk); pka(ac0, t_); \
    t_.x = __shfl_xor(ac1.x, msk); t_.y = __shfl_xor(ac1.y, msk); pka(ac1, t_); \
    t_.x = __shfl_xor(ac2.x, msk); t_.y = __shfl_xor(ac2.y, msk); pka(ac2, t_); \
    t_.x = __shfl_xor(ac3.x, msk); t_.y = __shfl_xor(ac3.y, msk); pka(ac3, t_); }

// ---------------- gather1 + gemm2 fused (R4-proven body): 2 nodes/wave,
// 4 slots x 8 fgroups, 6 predicated upfront batches, pre-scaled Hs1 (plain adds).
__global__ __launch_bounds__(256) void gather1_fused_kernel(const int* __restrict__ offs,
                                                            const int* __restrict__ ends,
                                                            const float* __restrict__ dinv,
                                                            const ush* __restrict__ Hs,
                                                            const int* __restrict__ csr,
                                                            const float* __restrict__ b1,
                                                            const float* __restrict__ W2,
                                                            ush* __restrict__ Hs2) {
    // lane l (=lane&31, fg=l&7, es=l>>3) owns W2 rows fg*8..+8, cols es*8..+8 as a
    // contiguous 64-float block; stride 68 floats (272B) staggers lanes across banks.
    __shared__ __align__(16) float Wp[32 * 68];
    {
        int t = threadIdx.x;            // 2048 floats / 256 threads = 8 floats each
        int lp = t >> 3, r = t & 7;
        int srow = (lp & 7) * 8 + r, scol = (lp >> 3) * 8;
        float4 va = *(const float4*)&W2[srow * DOUT + scol];
        float4 vb = *(const float4*)&W2[srow * DOUT + scol + 4];
        *(float4*)&Wp[lp * 68 + r * 8] = va;
        *(float4*)&Wp[lp * 68 + r * 8 + 4] = vb;
    }
    __syncthreads();

    int wid = (blockIdx.x * 256 + threadIdx.x) >> 6;
    int lane = threadIdx.x & 63;
    int node = wid * 2 + (lane >> 5);
    if (node >= NN) return;
    int l = lane & 31;
    int es = l >> 3;                     // 4 edge slots (stride 4)
    int fg = l & 7;                      // 8 fgroups x 8 bf16 = 16 B
    int start = offs[node], end = ends[node];
    float dv = dinv[node];                                   // hoisted
    uint4 su = *(const uint4*)&Hs[node * DH + fg * 8];       // hoisted self-row
    f32x2 ac0 = {0.f, 0.f}, ac1 = {0.f, 0.f}, ac2 = {0.f, 0.f}, ac3 = {0.f, 0.f};

    int base = start + es;
    {   // 6 predicated batches, all loads in flight together (covers deg<=24)
        int p0 = base, p1 = base + 4, p2 = base + 8,
            p3 = base + 12, p4 = base + 16, p5 = base + 20;
        bool v0 = p0 < end, v1 = p1 < end, v2 = p2 < end,
             v3 = p3 < end, v4 = p4 < end, v5 = p5 < end;
        int s0 = csr[v0 ? p0 : 0], s1 = csr[v1 ? p1 : 0], s2 = csr[v2 ? p2 : 0],
            s3 = csr[v3 ? p3 : 0], s4 = csr[v4 ? p4 : 0], s5 = csr[v5 ? p5 : 0];
        uint4 u0 = *(const uint4*)&Hs[s0 * DH + fg * 8];
        uint4 u1 = *(const uint4*)&Hs[s1 * DH + fg * 8];
        uint4 u2 = *(const uint4*)&Hs[s2 * DH + fg * 8];
        uint4 u3 = *(const uint4*)&Hs[s3 * DH + fg * 8];
        uint4 u4 = *(const uint4*)&Hs[s4 * DH + fg * 8];
        uint4 u5 = *(const uint4*)&Hs[s5 * DH + fg * 8];
        ZINV(u0, v0) ZINV(u1, v1) ZINV(u2, v2)
        ZINV(u3, v3) ZINV(u4, v4) ZINV(u5, v5)
        ACCP(u0) ACCP(u1) ACCP(u2) ACCP(u3) ACCP(u4) ACCP(u5)
    }
    for (int k = base + 24; k < end; k += 4) {   // rare overflow (deg>24, ~2%)
        int s = csr[k];
        uint4 u = *(const uint4*)&Hs[s * DH + fg * 8];
        ACCP(u)
    }
    // butterfly over es (bits 3,4): every lane gets full neighbor sums for its fgroup
    BFLY(8) BFLY(16)

    float4 ba = *(const float4*)&b1[fg * 8];
    float4 bb = *(const float4*)&b1[fg * 8 + 4];
    f32x2 dvp; dvp.x = dv; dvp.y = dv;
    // h = relu(dv*(acc + self) + b1), pure f32
    pka(ac0, up2(su.x)); pka(ac1, up2(su.y)); pka(ac2, up2(su.z)); pka(ac3, up2(su.w));
    f32x2 h0; h0.x = ba.x; h0.y = ba.y;
    f32x2 h1; h1.x = ba.z; h1.y = ba.w;
    f32x2 h2; h2.x = bb.x; h2.y = bb.y;
    f32x2 h3; h3.x = bb.z; h3.y = bb.w;
    pkfma(h0, dvp, ac0); pkfma(h1, dvp, ac1); pkfma(h2, dvp, ac2); pkfma(h3, dvp, ac3);
    h0.x = fmaxf(h0.x, 0.f); h0.y = fmaxf(h0.y, 0.f);
    h1.x = fmaxf(h1.x, 0.f); h1.y = fmaxf(h1.y, 0.f);
    h2.x = fmaxf(h2.x, 0.f); h2.y = fmaxf(h2.y, 0.f);
    h3.x = fmaxf(h3.x, 0.f); h3.y = fmaxf(h3.y, 0.f);

    // per-lane 8x8 block of h1@W2: p[c-pair] += h[r] * W2[fg*8+r][es*8 + c-pair]
    const float* wl = &Wp[l * 68];
    float hs_[8] = {h0.x, h0.y, h1.x, h1.y, h2.x, h2.y, h3.x, h3.y};
    f32x2 p0 = {0.f, 0.f}, p1 = {0.f, 0.f}, p2 = {0.f, 0.f}, p3 = {0.f, 0.f};
#pragma unroll
    for (int r = 0; r < 8; r++) {
        float4 wa = *(const float4*)&wl[r * 8];
        float4 wb = *(const float4*)&wl[r * 8 + 4];
        f32x2 hr; hr.x = hs_[r]; hr.y = hs_[r];
        f32x2 w01; w01.x = wa.x; w01.y = wa.y;
        f32x2 w23; w23.x = wa.z; w23.y = wa.w;
        f32x2 w45; w45.x = wb.x; w45.y = wb.y;
        f32x2 w67; w67.x = wb.z; w67.y = wb.w;
        pkfma(p0, hr, w01); pkfma(p1, hr, w23);
        pkfma(p2, hr, w45); pkfma(p3, hr, w67);
    }
    // butterfly over fg (bits 0..2): full column sums on every lane
#pragma unroll
    for (int msk = 1; msk <= 4; msk <<= 1) {
        f32x2 t_;
        t_.x = __shfl_xor(p0.x, msk); t_.y = __shfl_xor(p0.y, msk); pka(p0, t_);
        t_.x = __shfl_xor(p1.x, msk); t_.y = __shfl_xor(p1.y, msk); pka(p1, t_);
        t_.x = __shfl_xor(p2.x, msk); t_.y = __shfl_xor(p2.y, msk); pka(p2, t_);
        t_.x = __shfl_xor(p3.x, msk); t_.y = __shfl_xor(p3.y, msk); pka(p3, t_);
    }
    if (fg == 0) {
        pkmul(p0, dvp); pkmul(p1, dvp); pkmul(p2, dvp); pkmul(p3, dvp);
        ushort4 oa, ob;
        oa.x = f2bf(p0.x); oa.y = f2bf(p0.y); oa.z = f2bf(p1.x); oa.w = f2bf(p1.y);
        ob.x = f2bf(p2.x); ob.y = f2bf(p2.y); ob.z = f2bf(p3.x); ob.w = f2bf(p3.y);
        *(ushort4*)&Hs2[node * DOUT + es * 8] = oa;
        *(ushort4*)&Hs2[node * DOUT + es * 8 + 4] = ob;
    }
}

// ---------------- gather2 (R4-proven body): 2 nodes/wave, 8 slots x 4 fgroups + fc ----
__global__ __launch_bounds__(256) void gather2_kernel(const int* __restrict__ offs,
                                                      const int* __restrict__ ends,
                                                      const float* __restrict__ dinv,
                                                      const ush* __restrict__ Hs,
                                                      const int* __restrict__ csr,
                                                      const float* __restrict__ b2,
                                                      const float* __restrict__ fcw,
                                                      const float* __restrict__ fcb,
                                                      float* __restrict__ h2,
                                                      float* __restrict__ scores) {
    int wid = (blockIdx.x * 256 + threadIdx.x) >> 6;
    int lane = threadIdx.x & 63;
    int node = wid * 2 + (lane >> 5);
    if (node >= NN) return;
    int l = lane & 31;
    int es = l >> 2;                     // 8 edge slots (stride 8)
    int fg = l & 3;                      // 4 fgroups x 8 bf16 = 16 B
    int start = offs[node], end = ends[node];
    float dv = dinv[node];                                   // hoisted
    uint4 su = *(const uint4*)&Hs[node * DOUT + fg * 8];     // hoisted self-row
    f32x2 ac0 = {0.f, 0.f}, ac1 = {0.f, 0.f}, ac2 = {0.f, 0.f}, ac3 = {0.f, 0.f};

    int base = start + es;
    {   // 4 predicated batches, all loads in flight together (covers deg<=32)
        int p0 = base, p1 = base + 8, p2 = base + 16, p3 = base + 24;
        bool v0 = p0 < end, v1 = p1 < end, v2 = p2 < end, v3 = p3 < end;
        int s0 = csr[v0 ? p0 : 0], s1 = csr[v1 ? p1 : 0],
            s2 = csr[v2 ? p2 : 0], s3 = csr[v3 ? p3 : 0];
        uint4 u0 = *(const uint4*)&Hs[s0 * DOUT + fg * 8];
        uint4 u1 = *(const uint4*)&Hs[s1 * DOUT + fg * 8];
        uint4 u2 = *(const uint4*)&Hs[s2 * DOUT + fg * 8];
        uint4 u3 = *(const uint4*)&Hs[s3 * DOUT + fg * 8];
        ZINV(u0, v0) ZINV(u1, v1) ZINV(u2, v2) ZINV(u3, v3)
        ACCP(u0) ACCP(u1) ACCP(u2) ACCP(u3)
    }
    for (int k = base + 32; k < end; k += 8) {   // ultra-rare overflow (deg>32)
        int s = csr[k];
        uint4 u = *(const uint4*)&Hs[s * DOUT + fg * 8];
        ACCP(u)
    }
    // butterfly over es (bits 2,3,4)
    BFLY(4) BFLY(8) BFLY(16)

    float4 ba = *(const float4*)&b2[fg * 8];
    float4 bb = *(const float4*)&b2[fg * 8 + 4];
    f32x2 dvp; dvp.x = dv; dvp.y = dv;
    pka(ac0, up2(su.x)); pka(ac1, up2(su.y)); pka(ac2, up2(su.z)); pka(ac3, up2(su.w));
    f32x2 h0; h0.x = ba.x; h0.y = ba.y;
    f32x2 h1; h1.x = ba.z; h1.y = ba.w;
    f32x2 h2v; h2v.x = bb.x; h2v.y = bb.y;
    f32x2 h3; h3.x = bb.z; h3.y = bb.w;
    pkfma(h0, dvp, ac0); pkfma(h1, dvp, ac1); pkfma(h2v, dvp, ac2); pkfma(h3, dvp, ac3);
    h0.x = fmaxf(h0.x, 0.f); h0.y = fmaxf(h0.y, 0.f);
    h1.x = fmaxf(h1.x, 0.f); h1.y = fmaxf(h1.y, 0.f);
    h2v.x = fmaxf(h2v.x, 0.f); h2v.y = fmaxf(h2v.y, 0.f);
    h3.x = fmaxf(h3.x, 0.f); h3.y = fmaxf(h3.y, 0.f);
    if (es == 0) {
        float4 o0, o1;
        o0.x = h0.x; o0.y = h0.y; o0.z = h1.x; o0.w = h1.y;
        o1.x = h2v.x; o1.y = h2v.y; o1.z = h3.x; o1.w = h3.y;
        *(float4*)&h2[node * DOUT + fg * 8] = o0;
        *(float4*)&h2[node * DOUT + fg * 8 + 4] = o1;
    }
    float4 fa = *(const float4*)&fcw[fg * 8];
    float4 fb = *(const float4*)&fcw[fg * 8 + 4];
    f32x2 dp = {0.f, 0.f};
    f32x2 f01; f01.x = fa.x; f01.y = fa.y;
    f32x2 f23; f23.x = fa.z; f23.y = fa.w;
    f32x2 f45; f45.x = fb.x; f45.y = fb.y;
    f32x2 f67; f67.x = fb.z; f67.y = fb.w;
    pkfma(dp, h0, f01); pkfma(dp, h1, f23); pkfma(dp, h2v, f45); pkfma(dp, h3, f67);
    float sv = dp.x + dp.y;
    sv += __shfl_xor(sv, 1); sv += __shfl_xor(sv, 2);
    if (l == 0) scores[node] = sv + fcb[0];
}

extern "C" void kernel_launch(void* const* d_in, const int* in_sizes, int n_in,
                              void* d_out, int out_size, void* d_ws, size_t ws_size,
                              hipStream_t stream) {
    const float* x   = (const float*)d_in[0];
    const int*   ei  = (const int*)d_in[1];
    const float* W1  = (const float*)d_in[2];
    const float* b1  = (const float*)d_in[3];
    const float* W2  = (const float*)d_in[4];
    const float* b2  = (const float*)d_in[5];
    const float* fcw = (const float*)d_in[6];
    const float* fcb = (const float*)d_in[7];
    const int* src = ei;
    const int* dst = ei + EE;

    // Workspace layout (float-index units), verified by R6 passing:
    // Hs1 = NN*64 bf16 = 3,200,000 floats -> [3905024, 7105024); Hs2 follows.
    float* ws = (float*)d_ws;
    float* dinv    = ws;                          // NN f
    int*   offs    = (int*)(ws + 100352);         // NN
    int*   ends    = (int*)(ws + 200704);         // NN
    int*   bcur    = (int*)(ws + 301056);         // NBUCK
    int*   csr     = (int*)(ws + 301568);         // NBUCK*BCAP
    unsigned* tmp  = (unsigned*)(ws + 2103296);   // NBUCK*BCAP
    ush*   Hs1     = (ush*)(ws + 3905024);        // NN*64 bf16 [3905024, 7105024)
    ush*   Hs2     = (ush*)(ws + 7105024);        // NN*32 bf16 [7105024, 8705024)

    float* out    = (float*)d_out;
    float* scores = out;          // NN
    float* h2     = out + NN;     // NN*32

    const int T = 256;
    init_bcur_kernel<<<2, 256, 0, stream>>>(bcur);
    // fat dispatch: binA (edge binning) || gemm1 RAW (no dinv dep) — R6-proven
    fatAG_kernel<<<NCHUNK + GEMMB, T, 0, stream>>>(src, dst, bcur, tmp, x, W1, Hs1);
    // binB + in-place Hs1 scaling (raw -> pre-scaled)
    binBs_kernel<<<NBUCK, T, 0, stream>>>(tmp, bcur, csr, offs, ends, dinv, Hs1);
    // layer 1 gather + layer 2 transform fused (pre-scaled Hs1, R4-proven body)
    gather1_fused_kernel<<<(NN / 2 * 64 + T - 1) / T, T, 0, stream>>>(offs, ends, dinv, Hs1, csr, b1, W2, Hs2);
    // layer 2 gather + fc (R4-proven body)
    gather2_kernel<<<(NN / 2 * 64 + T - 1) / T, T, 0, stream>>>(offs, ends, dinv, Hs2, csr, b2, fcw, fcb, h2, scores);
}